// Round 1
// baseline (386.948 us; speedup 1.0000x reference)
//
#include <hip/hip_runtime.h>

#define ROW_LEN 128
#define EMPTY_SLOT 0xFFFFFFFFu

__global__ __launch_bounds__(256) void symfeat_kernel(
    const int* __restrict__ ids, const int* __restrict__ amask,
    const float* __restrict__ W1, const float* __restrict__ b1,
    const float* __restrict__ W2, const float* __restrict__ b2,
    float* __restrict__ out, int B)
{
    // LDS: 4 hash tables (one per wave) + staged MLP params
    __shared__ unsigned tbl[4][256];
    __shared__ float W1s[96];
    __shared__ float b1s[32];
    __shared__ float W2s[1024];
    __shared__ float b2s[32];

    const int t = threadIdx.x;

    // stage params + init all 4 hash tables, one barrier
    for (int i = t; i < 1024; i += 256) {
        W2s[i] = W2[i];
        ((unsigned*)tbl)[i] = EMPTY_SLOT;
    }
    if (t < 96) W1s[t] = W1[t];
    if (t < 32) { b1s[t] = b1[t]; b2s[t] = b2[t]; }
    __syncthreads();

    const int wave = t >> 6;   // 0..3
    const int lane = t & 63;
    const int row  = blockIdx.x * 4 + wave;
    if (row >= B) return;      // B = 262144 is divisible by 4; guard is cosmetic

    unsigned* mytbl = tbl[wave];

    // coalesced loads: lane i takes positions 2i, 2i+1 of this row
    const long vbase = (long)row * (ROW_LEN / 2) + lane; // in int2 units
    const int2 id2 = ((const int2*)ids)[vbase];
    const int2 mk2 = ((const int2*)amask)[vbase];

    int cnt = 0;   // newly-inserted (unique) tokens this lane contributed
    int sl  = 0;   // mask sum contribution

    if (mk2.x != 0) {
        sl++;
        const unsigned tok = (unsigned)id2.x;
        unsigned h = (tok * 2654435761u) >> 24;
        while (true) {
            unsigned old = atomicCAS(&mytbl[h], EMPTY_SLOT, tok);
            if (old == EMPTY_SLOT) { cnt++; break; }
            if (old == tok) break;
            h = (h + 1) & 255u;
        }
    }
    if (mk2.y != 0) {
        sl++;
        const unsigned tok = (unsigned)id2.y;
        unsigned h = (tok * 2654435761u) >> 24;
        while (true) {
            unsigned old = atomicCAS(&mytbl[h], EMPTY_SLOT, tok);
            if (old == EMPTY_SLOT) { cnt++; break; }
            if (old == tok) break;
            h = (h + 1) & 255u;
        }
    }

    // packed wave-64 reduction: low 16 bits = seq_len, high 16 = uniq
    unsigned packed = (unsigned)sl | ((unsigned)cnt << 16);
    #pragma unroll
    for (int off = 32; off > 0; off >>= 1)
        packed += __shfl_down(packed, off, 64);
    packed = __shfl(packed, 0, 64);  // broadcast total to all lanes

    const int seq  = (int)(packed & 0xFFFFu);
    const int uniq = (int)(packed >> 16);

    const float f0 = (float)seq  * (1.0f / 128.0f);
    const float f1 = (float)uniq * (1.0f / 128.0f);
    const float f2 = (seq > 0) ? ((float)uniq / (float)seq) : 0.0f;

    // layer 1: lane j (and j+32, redundantly) computes h[j]
    const int j = lane & 31;
    float hv = b1s[j];
    hv = fmaf(f0, W1s[j],      hv);
    hv = fmaf(f1, W1s[32 + j], hv);
    hv = fmaf(f2, W1s[64 + j], hv);
    hv = fmaxf(hv, 0.0f);

    // layer 2: lane k accumulates over all 32 h via uniform-index shuffle
    const int k = j;
    float acc = b2s[k];
    #pragma unroll
    for (int jj = 0; jj < 32; ++jj) {
        const float hj = __shfl(hv, jj, 64);
        acc = fmaf(hj, W2s[jj * 32 + k], acc);
    }
    acc = fmaxf(acc, 0.0f);

    if (lane < 32) out[(long)row * 32 + k] = acc;
}

extern "C" void kernel_launch(void* const* d_in, const int* in_sizes, int n_in,
                              void* d_out, int out_size, void* d_ws, size_t ws_size,
                              hipStream_t stream) {
    const int*   ids   = (const int*)d_in[0];
    const int*   amask = (const int*)d_in[1];
    const float* W1    = (const float*)d_in[2];
    const float* b1    = (const float*)d_in[3];
    const float* W2    = (const float*)d_in[4];
    const float* b2    = (const float*)d_in[5];
    float* out = (float*)d_out;

    const int B = in_sizes[0] / ROW_LEN;          // 262144
    const int blocks = (B + 3) / 4;               // 4 rows (waves) per block

    symfeat_kernel<<<blocks, 256, 0, stream>>>(ids, amask, W1, b1, W2, b2, out, B);
}